// Round 7
// baseline (327.800 us; speedup 1.0000x reference)
//
#include <hip/hip_runtime.h>
#include <hip/hip_bf16.h>
#include <math.h>

#define NNODES 10000
#define NEDGES 160000
#define EDIM   256
#define HIDC   128
#define TLEN   64
#define VOCAB  50257
#define NEG    0.2f

typedef __bf16 bf16x8 __attribute__((ext_vector_type(8)));
typedef float  f32x4  __attribute__((ext_vector_type(4)));
typedef unsigned short u16x8 __attribute__((ext_vector_type(8)));

static __device__ __forceinline__ float leaky(float x){ return x > 0.f ? x : NEG*x; }
static __device__ __forceinline__ float sigm (float x){ return __fdividef(1.f, 1.f + __expf(-x)); }
static __device__ __forceinline__ float eluf (float x){ return x > 0.f ? x : expm1f(x); }
static __device__ __forceinline__ unsigned short bf16rn(float f){
  unsigned a = __float_as_uint(f);
  return (unsigned short)((a + 0x7FFFu + ((a >> 16) & 1u)) >> 16);
}
static __device__ __forceinline__ float upf(unsigned short u){ return __uint_as_float(((unsigned)u) << 16); }

// ---------------- prep kernels ----------------
__global__ void k_featsb(const int* __restrict__ xn, const float* __restrict__ emb,
                         unsigned short* __restrict__ featsb){
  int node = blockIdx.x*4 + (threadIdx.x >> 6);
  int l = threadIdx.x & 63;
  float4 v = ((const float4*)(emb + (size_t)xn[node]*EDIM))[l];
  ushort4 o; o.x = bf16rn(v.x); o.y = bf16rn(v.y); o.z = bf16rn(v.z); o.w = bf16rn(v.w);
  *(ushort4*)(featsb + (size_t)node*EDIM + 4*l) = o;
}

// f32 -> bf16 cast (vector of 4), for Wout
__global__ void k_wcast(const float* __restrict__ in, unsigned short* __restrict__ out, int n4){
  int idx = blockIdx.x*256 + threadIdx.x;
  if (idx < n4){
    float4 v = ((const float4*)in)[idx];
    ushort4 o; o.x = bf16rn(v.x); o.y = bf16rn(v.y); o.z = bf16rn(v.z); o.w = bf16rn(v.w);
    ((ushort4*)out)[idx] = o;
  }
}

// transpose+bf16: in [K][Nin] f32 -> out [Nin][K] bf16 (out pre-offset). grid(K/64, Nin/64)
__global__ __launch_bounds__(256) void k_tr(const float* __restrict__ in,
    unsigned short* __restrict__ out, int K, int Nin)
{
  __shared__ unsigned short tile[64][72];
  int k0 = blockIdx.x*64, n0 = blockIdx.y*64;
  int t = threadIdx.x;
  int tr = t >> 4, tc4 = (t & 15)*4;
  #pragma unroll
  for (int it = 0; it < 4; ++it){
    int kr = tr + 16*it;
    float4 v = *(const float4*)(in + (size_t)(k0+kr)*Nin + n0 + tc4);
    tile[tc4+0][kr] = bf16rn(v.x);
    tile[tc4+1][kr] = bf16rn(v.y);
    tile[tc4+2][kr] = bf16rn(v.z);
    tile[tc4+3][kr] = bf16rn(v.w);
  }
  __syncthreads();
  #pragma unroll
  for (int it = 0; it < 4; ++it){
    int nr = tr + 16*it;
    ushort4 o;
    o.x = tile[nr][tc4+0]; o.y = tile[nr][tc4+1];
    o.z = tile[nr][tc4+2]; o.w = tile[nr][tc4+3];
    *(ushort4*)(out + (size_t)(n0+nr)*K + k0 + tc4) = o;
  }
}

// ---------------- CSR build ----------------
__global__ void k_deg(const int* __restrict__ dst, int* __restrict__ deg){
  int e = blockIdx.x*256 + threadIdx.x;
  if (e < NEDGES) atomicAdd(&deg[dst[e]], 1);
}

__global__ __launch_bounds__(1024) void k_scan(const int* __restrict__ deg, int* __restrict__ offs){
  __shared__ int s[1024];
  int t = threadIdx.x;
  int loc[10]; int sum = 0;
  #pragma unroll
  for (int q = 0; q < 10; q++){
    int idx = t*10 + q;
    loc[q] = sum;
    sum += (idx < NNODES) ? deg[idx] : 0;
  }
  s[t] = sum;
  __syncthreads();
  for (int ofs = 1; ofs < 1024; ofs <<= 1){
    int v = (t >= ofs) ? s[t-ofs] : 0;
    __syncthreads();
    s[t] += v;
    __syncthreads();
  }
  int pre = (t > 0) ? s[t-1] : 0;
  #pragma unroll
  for (int q = 0; q < 10; q++){
    int idx = t*10 + q;
    if (idx < NNODES) offs[idx] = pre + loc[q];
  }
  if (t == 1023) offs[NNODES] = s[1023];
}

__global__ void k_scatter(const int* __restrict__ src, const int* __restrict__ dst,
                          const int* __restrict__ offs, int* __restrict__ cursor,
                          int* __restrict__ esrc){
  int e = blockIdx.x*256 + threadIdx.x;
  if (e >= NEDGES) return;
  int d = dst[e];
  int p = atomicAdd(&cursor[d], 1);
  esrc[offs[d] + p] = src[e];
}

// ---------------- bf16 MFMA GEMM: C[M,N]=A[M,K]@Bt[N,K]^T ----------------
// 128x128 tile, 4 waves (2x2), BK=64, global_load_lds(16B) staging, bf16 out.
template<int KDIM>
__global__ __launch_bounds__(256) void k_mfma(const unsigned short* __restrict__ A,
    const unsigned short* __restrict__ Bt, unsigned short* __restrict__ C,
    int M, int N)
{
  __shared__ __align__(16) unsigned short As[128*64];
  __shared__ __align__(16) unsigned short Bs[128*64];
  int tid = threadIdx.x;
  int l   = tid & 63;
  int wid = tid >> 6;
  int wr = wid >> 1, wc = wid & 1;
  int row0 = blockIdx.x * 128, col0 = blockIdx.y * 128;
  int lr = l & 15, kg = l >> 4;
  f32x4 acc[4][4] = {};

  for (int kt = 0; kt < KDIM/64; ++kt){
    int k0 = kt*64;
    #pragma unroll
    for (int c = 0; c < 4; ++c){
      int chunk = wid*4 + c;                       // 0..15, 8 rows each
      int arow = row0 + chunk*8 + (l >> 3);
      if (arow > M-1) arow = M-1;
      const unsigned short* ga = A + (size_t)arow*KDIM + k0 + (l & 7)*8;
      __builtin_amdgcn_global_load_lds(
          (const __attribute__((address_space(1))) void*)ga,
          (__attribute__((address_space(3))) void*)(As + chunk*512), 16, 0, 0);
      int brow = col0 + chunk*8 + (l >> 3);        // N is a multiple of 128
      const unsigned short* gb = Bt + (size_t)brow*KDIM + k0 + (l & 7)*8;
      __builtin_amdgcn_global_load_lds(
          (const __attribute__((address_space(1))) void*)gb,
          (__attribute__((address_space(3))) void*)(Bs + chunk*512), 16, 0, 0);
    }
    __syncthreads();
    #pragma unroll
    for (int ks = 0; ks < 2; ++ks){
      bf16x8 af[4], bfr[4];
      #pragma unroll
      for (int m = 0; m < 4; ++m)
        af[m] = *(const bf16x8*)(As + (wr*64 + m*16 + lr)*64 + ks*32 + kg*8);
      #pragma unroll
      for (int n = 0; n < 4; ++n)
        bfr[n] = *(const bf16x8*)(Bs + (wc*64 + n*16 + lr)*64 + ks*32 + kg*8);
      #pragma unroll
      for (int m = 0; m < 4; ++m)
        #pragma unroll
        for (int n = 0; n < 4; ++n)
          acc[m][n] = __builtin_amdgcn_mfma_f32_16x16x32_bf16(af[m], bfr[n], acc[m][n], 0, 0, 0);
    }
    __syncthreads();
  }

  #pragma unroll
  for (int m = 0; m < 4; ++m){
    int rbase = row0 + wr*64 + m*16 + kg*4;
    #pragma unroll
    for (int r = 0; r < 4; ++r){
      int row = rbase + r;
      if (row < M){
        #pragma unroll
        for (int n = 0; n < 4; ++n){
          int col = col0 + wc*64 + n*16 + lr;
          C[(size_t)row*N + col] = bf16rn(acc[m][n][r]);
        }
      }
    }
  }
}

// ---------------- output projection: out[t][v] = HTt[t,:]·Woutb[v,:] + bout[v] ----------------
// M=64 (t), N=VOCAB (v), K=128. 4 waves; block tile N=128; A(16KB)+B(32KB) in LDS.
__global__ __launch_bounds__(256) void k_mout(const unsigned short* __restrict__ A,
    const unsigned short* __restrict__ Bt, const float* __restrict__ bias,
    float* __restrict__ out)
{
  __shared__ __align__(16) unsigned short As[64*128];
  __shared__ __align__(16) unsigned short Bs[128*128];
  int tid = threadIdx.x;
  int l   = tid & 63;
  int wid = tid >> 6;
  int col0 = blockIdx.x * 128;
  int lr = l & 15, kg = l >> 4;

  #pragma unroll
  for (int c = 0; c < 4; ++c){                     // A: 16 chunks of 1KB (4 rows each)
    int chunk = wid*4 + c;
    const unsigned short* ga = A + (size_t)(chunk*4 + (l >> 4))*128 + (l & 15)*8;
    __builtin_amdgcn_global_load_lds(
        (const __attribute__((address_space(1))) void*)ga,
        (__attribute__((address_space(3))) void*)(As + chunk*512), 16, 0, 0);
  }
  #pragma unroll
  for (int c = 0; c < 8; ++c){                     // B: 32 chunks of 1KB (4 rows each)
    int chunk = wid*8 + c;
    int brow = col0 + chunk*4 + (l >> 4);
    if (brow > VOCAB-1) brow = VOCAB-1;
    const unsigned short* gb = Bt + (size_t)brow*128 + (l & 15)*8;
    __builtin_amdgcn_global_load_lds(
        (const __attribute__((address_space(1))) void*)gb,
        (__attribute__((address_space(3))) void*)(Bs + chunk*512), 16, 0, 0);
  }
  __syncthreads();

  f32x4 acc[4][2] = {};
  #pragma unroll
  for (int ks = 0; ks < 4; ++ks){
    bf16x8 af[4], bfr[2];
    #pragma unroll
    for (int m = 0; m < 4; ++m)
      af[m] = *(const bf16x8*)(As + (m*16 + lr)*128 + ks*32 + kg*8);
    #pragma unroll
    for (int n = 0; n < 2; ++n)
      bfr[n] = *(const bf16x8*)(Bs + (wid*32 + n*16 + lr)*128 + ks*32 + kg*8);
    #pragma unroll
    for (int m = 0; m < 4; ++m)
      #pragma unroll
      for (int n = 0; n < 2; ++n)
        acc[m][n] = __builtin_amdgcn_mfma_f32_16x16x32_bf16(af[m], bfr[n], acc[m][n], 0, 0, 0);
  }

  #pragma unroll
  for (int n = 0; n < 2; ++n){
    int col = col0 + wid*32 + n*16 + lr;
    if (col < VOCAB){
      float bv = bias[col];
      #pragma unroll
      for (int m = 0; m < 4; ++m){
        #pragma unroll
        for (int r = 0; r < 4; ++r){
          int trow = m*16 + kg*4 + r;              // t in 0..63
          out[(size_t)trow*VOCAB + col] = acc[m][n][r] + bv;
        }
      }
    }
  }
}

// ---------------- GAT layer 1 (heads=4, 128ch), bf16 in/out, wave/node ----------------
__global__ __launch_bounds__(256) void k_gat1(const unsigned short* __restrict__ xlr,
    const int* __restrict__ esrc, const int* __restrict__ offs,
    const float* __restrict__ att, const float* __restrict__ b1,
    unsigned short* __restrict__ h1b)
{
  int node = blockIdx.x*4 + (threadIdx.x >> 6);
  int l = threadIdx.x & 63;
  const unsigned short* bi = xlr + (size_t)node*1024;
  ushort4 u;
  u = *(const ushort4*)(bi + 512 + 4*l);
  float4 xr1; xr1.x = upf(u.x); xr1.y = upf(u.y); xr1.z = upf(u.z); xr1.w = upf(u.w);
  u = *(const ushort4*)(bi + 768 + 4*l);
  float4 xr2; xr2.x = upf(u.x); xr2.y = upf(u.y); xr2.z = upf(u.z); xr2.w = upf(u.w);
  int hq = l >> 5;
  float4 at1 = *(const float4*)(att + hq*HIDC + ((4*l) & 127));
  float4 at2 = *(const float4*)(att + (2+hq)*HIDC + ((4*l) & 127));
  float4 ac1 = {0,0,0,0}, ac2 = {0,0,0,0};
  float d1 = 0.f, d2 = 0.f;
  int beg = offs[node], end = offs[node+1];
  for (int p = beg-1; p < end; ++p){
    int s = (p < beg) ? node : esrc[p];
    const unsigned short* bs = xlr + (size_t)s*1024;
    ushort4 u1 = *(const ushort4*)(bs + 4*l);
    ushort4 u2 = *(const ushort4*)(bs + 256 + 4*l);
    float4 x1; x1.x = upf(u1.x); x1.y = upf(u1.y); x1.z = upf(u1.z); x1.w = upf(u1.w);
    float4 x2; x2.x = upf(u2.x); x2.y = upf(u2.y); x2.z = upf(u2.z); x2.w = upf(u2.w);
    float p1 = leaky(x1.x+xr1.x)*at1.x + leaky(x1.y+xr1.y)*at1.y
             + leaky(x1.z+xr1.z)*at1.z + leaky(x1.w+xr1.w)*at1.w;
    float p2 = leaky(x2.x+xr2.x)*at2.x + leaky(x2.y+xr2.y)*at2.y
             + leaky(x2.z+xr2.z)*at2.z + leaky(x2.w+xr2.w)*at2.w;
    #pragma unroll
    for (int m = 1; m <= 16; m <<= 1){
      p1 += __shfl_xor(p1, m);
      p2 += __shfl_xor(p2, m);
    }
    float w1 = __expf(p1), w2 = __expf(p2);
    ac1.x = fmaf(w1, x1.x, ac1.x); ac1.y = fmaf(w1, x1.y, ac1.y);
    ac1.z = fmaf(w1, x1.z, ac1.z); ac1.w = fmaf(w1, x1.w, ac1.w);
    ac2.x = fmaf(w2, x2.x, ac2.x); ac2.y = fmaf(w2, x2.y, ac2.y);
    ac2.z = fmaf(w2, x2.z, ac2.z); ac2.w = fmaf(w2, x2.w, ac2.w);
    d1 += w1; d2 += w2;
  }
  float i1 = 1.f/d1, i2 = 1.f/d2;
  const float* bq1 = b1 + 4*l;
  const float* bq2 = b1 + 256 + 4*l;
  ushort4 o1, o2;
  o1.x = bf16rn(eluf(ac1.x*i1 + bq1[0])); o1.y = bf16rn(eluf(ac1.y*i1 + bq1[1]));
  o1.z = bf16rn(eluf(ac1.z*i1 + bq1[2])); o1.w = bf16rn(eluf(ac1.w*i1 + bq1[3]));
  o2.x = bf16rn(eluf(ac2.x*i2 + bq2[0])); o2.y = bf16rn(eluf(ac2.y*i2 + bq2[1]));
  o2.z = bf16rn(eluf(ac2.z*i2 + bq2[2])); o2.w = bf16rn(eluf(ac2.w*i2 + bq2[3]));
  *(ushort4*)(h1b + (size_t)node*512 + 4*l)       = o1;
  *(ushort4*)(h1b + (size_t)node*512 + 256 + 4*l) = o2;
}

// ---------------- GAT layer 2 (1 head, 128 ch), bf16 in, f32 out ----------------
__global__ __launch_bounds__(256) void k_gat2(const unsigned short* __restrict__ xlr2,
    const int* __restrict__ esrc, const int* __restrict__ offs,
    const float* __restrict__ att2, const float* __restrict__ b2,
    float* __restrict__ enc)
{
  int node = blockIdx.x*4 + (threadIdx.x >> 6);
  int l = threadIdx.x & 63;
  const unsigned short* bi = xlr2 + (size_t)node*256;
  ushort2 v = *(const ushort2*)(bi + 128 + 2*l);
  float2 xr; xr.x = upf(v.x); xr.y = upf(v.y);
  float2 at = *(const float2*)(att2 + 2*l);
  float2 ac = {0,0}; float den = 0.f;
  int beg = offs[node], end = offs[node+1];
  for (int p = beg-1; p < end; ++p){
    int s = (p < beg) ? node : esrc[p];
    ushort2 xv = *(const ushort2*)(xlr2 + (size_t)s*256 + 2*l);
    float2 x; x.x = upf(xv.x); x.y = upf(xv.y);
    float pp = leaky(x.x+xr.x)*at.x + leaky(x.y+xr.y)*at.y;
    #pragma unroll
    for (int m = 1; m <= 32; m <<= 1) pp += __shfl_xor(pp, m);
    float w = __expf(pp);
    ac.x = fmaf(w, x.x, ac.x); ac.y = fmaf(w, x.y, ac.y);
    den += w;
  }
  float inv = 1.f/den;
  float2 o; o.x = ac.x*inv + b2[2*l]; o.y = ac.y*inv + b2[2*l+1];
  *(float2*)(enc + (size_t)node*128 + 2*l) = o;
}

// ---------------- context mean ----------------
__global__ void k_mean(const float* __restrict__ enc, float* __restrict__ ctx){
  int c = threadIdx.x & 127;
  int slice = blockIdx.x*2 + (threadIdx.x >> 7);
  float s = 0.f;
  for (int i = slice; i < NNODES; i += 160) s += enc[(size_t)i*128 + c];
  atomicAdd(&ctx[c], s * (1.f/NNODES));
}

// ---------------- GRU input precompute: Gi[t] = Wih @ x_t + bih ----------------
__global__ __launch_bounds__(384) void k_gi(const int* __restrict__ tseq,
    const float* __restrict__ emb, const float* __restrict__ ctx,
    const float* __restrict__ Wih, const float* __restrict__ bih,
    float* __restrict__ Gi)
{
  __shared__ float xs[384];
  int t = blockIdx.x, tid = threadIdx.x;
  int tok = (t == 0) ? 0 : tseq[t-1];
  if (tid < 256) xs[tid] = emb[(size_t)tok*EDIM + tid];
  else           xs[tid] = ctx[tid - 256];
  __syncthreads();
  const float* w = Wih + (size_t)tid*384;
  float acc = bih[tid];
  #pragma unroll 8
  for (int k = 0; k < 384; k++) acc = fmaf(w[k], xs[k], acc);
  Gi[t*384 + tid] = acc;
}

// ---------------- GRU recurrence: 4 waves, gate-aligned MFMA tiling ----------------
// R7: wave w owns rows [w*32, w*32+32) of ALL THREE gate blocks:
//   r-gate tiles {2w,2w+1}, z-gate {8+2w,8+2w+1}, n-gate {16+2w,16+2w+1}.
// After 48 MFMAs (6 tiles x 4 ks x hi/lo), each lane holds GH_r/GH_z/GH_n for its
// 8 rows IN REGISTERS -> gates computed in-place (no GH LDS round trip, no
// gate-wave asymmetry). h ping-pong in LDS kills the intra-step race with ONE
// barrier per step. Whh A-frags persist in VGPRs; h split hi+lo bf16.
__global__ __launch_bounds__(256) void k_gru(const float* __restrict__ Gi,
    const float* __restrict__ Whh, const float* __restrict__ bhh,
    unsigned short* __restrict__ HTt)
{
  __shared__ __align__(16) unsigned short hbuf[2][2][128];   // [pingpong][hi/lo][128]
  int tid = threadIdx.x;
  int l = tid & 63, w = tid >> 6;       // 4 waves
  int lr = l & 15, kg = l >> 4;

  // A-fragments: afr[g][s][ks], row = g*128 + w*32 + s*16 + lr, k = ks*32 + kg*8 + j
  bf16x8 afr[3][2][4];
  float  bh [3][2][4];
  #pragma unroll
  for (int g = 0; g < 3; ++g){
    #pragma unroll
    for (int s = 0; s < 2; ++s){
      int row = g*128 + w*32 + s*16 + lr;
      const float* rp = Whh + (size_t)row*HIDC;
      #pragma unroll
      for (int ks = 0; ks < 4; ++ks){
        const float* p = rp + ks*32 + kg*8;
        float4 v0 = *(const float4*)p;
        float4 v1 = *(const float4*)(p + 4);
        u16x8 u;
        u[0] = bf16rn(v0.x); u[1] = bf16rn(v0.y); u[2] = bf16rn(v0.z); u[3] = bf16rn(v0.w);
        u[4] = bf16rn(v1.x); u[5] = bf16rn(v1.y); u[6] = bf16rn(v1.z); u[7] = bf16rn(v1.w);
        afr[g][s][ks] = __builtin_bit_cast(bf16x8, u);
      }
      int rb = g*128 + w*32 + s*16 + kg*4;
      #pragma unroll
      for (int r = 0; r < 4; ++r) bh[g][s][r] = bhh[rb + r];
    }
  }

  float hloc[2][4] = {};                 // h for rows w*32 + s*16 + kg*4 + r
  if (tid < 128){ hbuf[0][0][tid] = 0; hbuf[0][1][tid] = 0; }
  __syncthreads();

  for (int t = 0; t < TLEN; t++){
    // prefetch Gi for this lane's rows (consumed after MFMAs -> latency hidden)
    f32x4 gi[3][2];
    #pragma unroll
    for (int g = 0; g < 3; ++g)
      #pragma unroll
      for (int s = 0; s < 2; ++s)
        gi[g][s] = *(const f32x4*)(Gi + t*384 + g*128 + w*32 + s*16 + kg*4);

    int rb = t & 1, wb = rb ^ 1;
    bf16x8 bhi[4], blo[4];
    #pragma unroll
    for (int ks = 0; ks < 4; ++ks){
      bhi[ks] = *(const bf16x8*)(&hbuf[rb][0][ks*32 + kg*8]);
      blo[ks] = *(const bf16x8*)(&hbuf[rb][1][ks*32 + kg*8]);
    }
    f32x4 acc[3][2] = {};
    #pragma unroll
    for (int ks = 0; ks < 4; ++ks){
      #pragma unroll
      for (int g = 0; g < 3; ++g){
        #pragma unroll
        for (int s = 0; s < 2; ++s){
          acc[g][s] = __builtin_amdgcn_mfma_f32_16x16x32_bf16(afr[g][s][ks], bhi[ks], acc[g][s], 0, 0, 0);
          acc[g][s] = __builtin_amdgcn_mfma_f32_16x16x32_bf16(afr[g][s][ks], blo[ks], acc[g][s], 0, 0, 0);
        }
      }
    }
    // gates fully in registers (every lane of a 16-lane column group redundantly)
    #pragma unroll
    for (int s = 0; s < 2; ++s){
      ushort4 hi4, lo4;
      unsigned short hv[4], lv[4];
      #pragma unroll
      for (int r = 0; r < 4; ++r){
        float gr = gi[0][s][r] + acc[0][s][r] + bh[0][s][r];
        float gz = gi[1][s][r] + acc[1][s][r] + bh[1][s][r];
        float hn = acc[2][s][r] + bh[2][s][r];
        float rr = sigm(gr);
        float z  = sigm(gz);
        float e2 = __expf(2.f*(gi[2][s][r] + rr*hn));
        float cand = __fdividef(e2 - 1.f, e2 + 1.f);
        float hnew = (1.f - z)*cand + z*hloc[s][r];
        hloc[s][r] = hnew;
        hv[r] = bf16rn(hnew);
        lv[r] = bf16rn(hnew - upf(hv[r]));
      }
      hi4.x = hv[0]; hi4.y = hv[1]; hi4.z = hv[2]; hi4.w = hv[3];
      lo4.x = lv[0]; lo4.y = lv[1]; lo4.z = lv[2]; lo4.w = lv[3];
      if (lr == 0){
        int row0 = w*32 + s*16 + kg*4;
        *(ushort4*)(&hbuf[wb][0][row0]) = hi4;
        *(ushort4*)(&hbuf[wb][1][row0]) = lo4;
        *(ushort4*)(HTt + t*HIDC + row0) = hi4;
      }
    }
    __syncthreads();
  }
}

// ---------------- launch ----------------
extern "C" void kernel_launch(void* const* d_in, const int* in_sizes, int n_in,
                              void* d_out, int out_size, void* d_ws, size_t ws_size,
                              hipStream_t stream)
{
  const int*   x_nodes = (const int*)  d_in[0];
  const int*   eidx    = (const int*)  d_in[1];   // [2][160000]: src then dst
  const int*   tseq    = (const int*)  d_in[2];
  const float* emb     = (const float*)d_in[3];
  const float* W1l     = (const float*)d_in[4];
  const float* W1r     = (const float*)d_in[5];
  const float* att1    = (const float*)d_in[6];
  const float* b1      = (const float*)d_in[7];
  const float* W2l     = (const float*)d_in[8];
  const float* W2r     = (const float*)d_in[9];
  const float* att2    = (const float*)d_in[10];
  const float* b2      = (const float*)d_in[11];
  const float* Wih     = (const float*)d_in[12];
  const float* Whh     = (const float*)d_in[13];
  const float* bih     = (const float*)d_in[14];
  const float* bhh     = (const float*)d_in[15];
  const float* Wout    = (const float*)d_in[16];
  const float* bout    = (const float*)d_in[17];
  float* out = (float*)d_out;
  char*  ws  = (char*)d_ws;

  // workspace layout (bytes), no aliasing
  unsigned short* xlr1b  = (unsigned short*)(ws);              // 10000*1024*2 = 20,480,000
  unsigned short* h1b    = (unsigned short*)(ws + 20480000);   // 10000*512*2  = 10,240,000
  unsigned short* featsb = (unsigned short*)(ws + 30720000);   // 10000*256*2  =  5,120,000
  unsigned short* xlr2b  = (unsigned short*)(ws + 35840000);   // 10000*256*2  =  5,120,000
  float*          enc    = (float*)        (ws + 40960000);    // 10000*128*4  =  5,120,000
  unsigned short* Bt1    = (unsigned short*)(ws + 46080000);   // 1024*256*2   =    524,288
  unsigned short* Bt2    = (unsigned short*)(ws + 46604288);   // 256*512*2    =    262,144
  int*   deg    = (int*)(ws + 46866432);                       // 40,000
  int*   offs   = (int*)(ws + 46906432);                       // 40,004
  int*   cursor = (int*)(ws + 46946436);                       // 40,000
  int*   esrc   = (int*)(ws + 46986436);                       // 640,000
  float* ctx    = (float*)(ws + 47626440);                     // 512
  float* Gi     = (float*)(ws + 47627008);                     // 98,304 (ends 47,725,312)
  unsigned short* HTt   = (unsigned short*)(ws + 47725312);    // 64*128*2 = 16,384
  unsigned short* Woutb = (unsigned short*)(ws + 47741696);    // 50257*128*2 = 12,865,792 (ends 60,607,488)

  hipMemsetAsync(deg,    0, NNODES*sizeof(int), stream);
  hipMemsetAsync(cursor, 0, NNODES*sizeof(int), stream);

  k_featsb<<<2500, 256, 0, stream>>>(x_nodes, emb, featsb);
  k_wcast <<<6283, 256, 0, stream>>>(Wout, Woutb, VOCAB*128/4);
  // Bt1[n][k]: n<512 from W1l[256][512], n>=512 from W1r
  k_tr<<<dim3(4,8), 256, 0, stream>>>(W1l, Bt1,            256, 512);
  k_tr<<<dim3(4,8), 256, 0, stream>>>(W1r, Bt1 + 512*256,  256, 512);
  // Bt2[n][k]: n<128 from W2l[512][128], n>=128 from W2r
  k_tr<<<dim3(8,2), 256, 0, stream>>>(W2l, Bt2,            512, 128);
  k_tr<<<dim3(8,2), 256, 0, stream>>>(W2r, Bt2 + 128*512,  512, 128);

  k_deg    <<<625, 256, 0, stream>>>(eidx + NEDGES, deg);
  k_scan   <<<1,  1024, 0, stream>>>(deg, offs);
  k_scatter<<<625, 256, 0, stream>>>(eidx, eidx + NEDGES, offs, cursor, esrc);

  k_mfma<256><<<dim3(79,8), 256, 0, stream>>>(featsb, Bt1, xlr1b, NNODES, 1024);
  k_gat1<<<2500, 256, 0, stream>>>(xlr1b, esrc, offs, att1, b1, h1b);

  k_mfma<512><<<dim3(79,2), 256, 0, stream>>>(h1b, Bt2, xlr2b, NNODES, 256);
  k_gat2<<<2500, 256, 0, stream>>>(xlr2b, esrc, offs, att2, b2, enc);

  hipMemsetAsync(ctx, 0, 128*sizeof(float), stream);
  k_mean<<<80, 256, 0, stream>>>(enc, ctx);
  k_gi  <<<TLEN, 384, 0, stream>>>(tseq, emb, ctx, Wih, bih, Gi);
  k_gru <<<1, 256, 0, stream>>>(Gi, Whh, bhh, HTt);

  k_mout<<<393, 256, 0, stream>>>(HTt, Woutb, bout, out);
}

// Round 8
// 259.576 us; speedup vs baseline: 1.2628x; 1.2628x over previous
//
#include <hip/hip_runtime.h>
#include <hip/hip_bf16.h>
#include <math.h>

#define NNODES 10000
#define NEDGES 160000
#define EDIM   256
#define HIDC   128
#define TLEN   64
#define VOCAB  50257
#define NEG    0.2f

typedef __bf16 bf16x8 __attribute__((ext_vector_type(8)));
typedef float  f32x4  __attribute__((ext_vector_type(4)));

static __device__ __forceinline__ float leaky(float x){ return x > 0.f ? x : NEG*x; }
static __device__ __forceinline__ float sigm (float x){ return __fdividef(1.f, 1.f + __expf(-x)); }
static __device__ __forceinline__ float eluf (float x){ return x > 0.f ? x : expm1f(x); }
static __device__ __forceinline__ unsigned short bf16rn(float f){
  unsigned a = __float_as_uint(f);
  return (unsigned short)((a + 0x7FFFu + ((a >> 16) & 1u)) >> 16);
}
static __device__ __forceinline__ float upf(unsigned short u){ return __uint_as_float(((unsigned)u) << 16); }

// ---------------- fused prep kernel ----------------
// blockIdx ranges: [0,2500) featsb | [2500,8783) wcast | [8783,8815) tr W1l |
// [8815,8847) tr W1r | [8847,8863) tr W2l | [8863,8879) tr W2r | [8879,8919) zero
#define PB_FEATS 2500
#define PB_WCAST 8783
#define PB_TR1L  8815
#define PB_TR1R  8847
#define PB_TR2L  8863
#define PB_TR2R  8879
#define PB_ZERO  8919

static __device__ void tr_dev(const float* __restrict__ in, unsigned short* __restrict__ out,
                              int K, int Nin, int bx, int by, int t,
                              unsigned short (*tile)[72])
{
  int k0 = bx*64, n0 = by*64;
  int tr = t >> 4, tc4 = (t & 15)*4;
  #pragma unroll
  for (int it = 0; it < 4; ++it){
    int kr = tr + 16*it;
    float4 v = *(const float4*)(in + (size_t)(k0+kr)*Nin + n0 + tc4);
    tile[tc4+0][kr] = bf16rn(v.x);
    tile[tc4+1][kr] = bf16rn(v.y);
    tile[tc4+2][kr] = bf16rn(v.z);
    tile[tc4+3][kr] = bf16rn(v.w);
  }
  __syncthreads();
  #pragma unroll
  for (int it = 0; it < 4; ++it){
    int nr = tr + 16*it;
    ushort4 o;
    o.x = tile[nr][tc4+0]; o.y = tile[nr][tc4+1];
    o.z = tile[nr][tc4+2]; o.w = tile[nr][tc4+3];
    *(ushort4*)(out + (size_t)(n0+nr)*K + k0 + tc4) = o;
  }
}

__global__ __launch_bounds__(256) void k_prep(
    const int* __restrict__ xn, const float* __restrict__ emb,
    unsigned short* __restrict__ featsb,
    const float* __restrict__ Wout, unsigned short* __restrict__ Woutb,
    const float* __restrict__ W1l, const float* __restrict__ W1r, unsigned short* __restrict__ Bt1,
    const float* __restrict__ W2l, const float* __restrict__ W2r, unsigned short* __restrict__ Bt2,
    int* __restrict__ deg, int* __restrict__ cursor, float* __restrict__ ctx)
{
  __shared__ unsigned short tile[64][72];
  int b = blockIdx.x, t = threadIdx.x;
  if (b < PB_FEATS){
    int node = b*4 + (t >> 6);
    int l = t & 63;
    float4 v = ((const float4*)(emb + (size_t)xn[node]*EDIM))[l];
    ushort4 o; o.x = bf16rn(v.x); o.y = bf16rn(v.y); o.z = bf16rn(v.z); o.w = bf16rn(v.w);
    *(ushort4*)(featsb + (size_t)node*EDIM + 4*l) = o;
  } else if (b < PB_WCAST){
    int idx = (b - PB_FEATS)*256 + t;
    if (idx < VOCAB*HIDC/4){
      float4 v = ((const float4*)Wout)[idx];
      ushort4 o; o.x = bf16rn(v.x); o.y = bf16rn(v.y); o.z = bf16rn(v.z); o.w = bf16rn(v.w);
      ((ushort4*)Woutb)[idx] = o;
    }
  } else if (b < PB_TR1L){
    int lb = b - PB_WCAST;  tr_dev(W1l, Bt1,           256, 512, lb & 3, lb >> 2, t, tile);
  } else if (b < PB_TR1R){
    int lb = b - PB_TR1L;   tr_dev(W1r, Bt1 + 512*256, 256, 512, lb & 3, lb >> 2, t, tile);
  } else if (b < PB_TR2L){
    int lb = b - PB_TR1R;   tr_dev(W2l, Bt2,           512, 128, lb & 7, lb >> 3, t, tile);
  } else if (b < PB_TR2R){
    int lb = b - PB_TR2L;   tr_dev(W2r, Bt2 + 128*512, 512, 128, lb & 7, lb >> 3, t, tile);
  } else {
    int gid = (b - PB_TR2R)*256 + t;
    if (gid < NNODES){ deg[gid] = 0; cursor[gid] = 0; }
    if (gid < HIDC) ctx[gid] = 0.f;
  }
}

// ---------------- CSR build ----------------
__global__ void k_deg(const int* __restrict__ dst, int* __restrict__ deg){
  int e = blockIdx.x*256 + threadIdx.x;
  if (e < NEDGES) atomicAdd(&deg[dst[e]], 1);
}

__global__ __launch_bounds__(1024) void k_scan(const int* __restrict__ deg, int* __restrict__ offs){
  __shared__ int s[1024];
  int t = threadIdx.x;
  int loc[10]; int sum = 0;
  #pragma unroll
  for (int q = 0; q < 10; q++){
    int idx = t*10 + q;
    loc[q] = sum;
    sum += (idx < NNODES) ? deg[idx] : 0;
  }
  s[t] = sum;
  __syncthreads();
  for (int ofs = 1; ofs < 1024; ofs <<= 1){
    int v = (t >= ofs) ? s[t-ofs] : 0;
    __syncthreads();
    s[t] += v;
    __syncthreads();
  }
  int pre = (t > 0) ? s[t-1] : 0;
  #pragma unroll
  for (int q = 0; q < 10; q++){
    int idx = t*10 + q;
    if (idx < NNODES) offs[idx] = pre + loc[q];
  }
  if (t == 1023) offs[NNODES] = s[1023];
}

__global__ void k_scatter(const int* __restrict__ src, const int* __restrict__ dst,
                          const int* __restrict__ offs, int* __restrict__ cursor,
                          int* __restrict__ esrc){
  int e = blockIdx.x*256 + threadIdx.x;
  if (e >= NEDGES) return;
  int d = dst[e];
  int p = atomicAdd(&cursor[d], 1);
  esrc[offs[d] + p] = src[e];
}

// ---------------- bf16 MFMA GEMM: C[M,N]=A[M,K]@Bt[N,K]^T ----------------
// 128x128 tile, 4 waves (2x2), BK=64, global_load_lds(16B) staging, bf16 out.
template<int KDIM>
__global__ __launch_bounds__(256) void k_mfma(const unsigned short* __restrict__ A,
    const unsigned short* __restrict__ Bt, unsigned short* __restrict__ C,
    int M, int N)
{
  __shared__ __align__(16) unsigned short As[128*64];
  __shared__ __align__(16) unsigned short Bs[128*64];
  int tid = threadIdx.x;
  int l   = tid & 63;
  int wid = tid >> 6;
  int wr = wid >> 1, wc = wid & 1;
  int row0 = blockIdx.x * 128, col0 = blockIdx.y * 128;
  int lr = l & 15, kg = l >> 4;
  f32x4 acc[4][4] = {};

  for (int kt = 0; kt < KDIM/64; ++kt){
    int k0 = kt*64;
    #pragma unroll
    for (int c = 0; c < 4; ++c){
      int chunk = wid*4 + c;                       // 0..15, 8 rows each
      int arow = row0 + chunk*8 + (l >> 3);
      if (arow > M-1) arow = M-1;
      const unsigned short* ga = A + (size_t)arow*KDIM + k0 + (l & 7)*8;
      __builtin_amdgcn_global_load_lds(
          (const __attribute__((address_space(1))) void*)ga,
          (__attribute__((address_space(3))) void*)(As + chunk*512), 16, 0, 0);
      int brow = col0 + chunk*8 + (l >> 3);        // N is a multiple of 128
      const unsigned short* gb = Bt + (size_t)brow*KDIM + k0 + (l & 7)*8;
      __builtin_amdgcn_global_load_lds(
          (const __attribute__((address_space(1))) void*)gb,
          (__attribute__((address_space(3))) void*)(Bs + chunk*512), 16, 0, 0);
    }
    __syncthreads();
    #pragma unroll
    for (int ks = 0; ks < 2; ++ks){
      bf16x8 af[4], bfr[4];
      #pragma unroll
      for (int m = 0; m < 4; ++m)
        af[m] = *(const bf16x8*)(As + (wr*64 + m*16 + lr)*64 + ks*32 + kg*8);
      #pragma unroll
      for (int n = 0; n < 4; ++n)
        bfr[n] = *(const bf16x8*)(Bs + (wc*64 + n*16 + lr)*64 + ks*32 + kg*8);
      #pragma unroll
      for (int m = 0; m < 4; ++m)
        #pragma unroll
        for (int n = 0; n < 4; ++n)
          acc[m][n] = __builtin_amdgcn_mfma_f32_16x16x32_bf16(af[m], bfr[n], acc[m][n], 0, 0, 0);
    }
    __syncthreads();
  }

  #pragma unroll
  for (int m = 0; m < 4; ++m){
    int rbase = row0 + wr*64 + m*16 + kg*4;
    #pragma unroll
    for (int r = 0; r < 4; ++r){
      int row = rbase + r;
      if (row < M){
        #pragma unroll
        for (int n = 0; n < 4; ++n){
          int col = col0 + wc*64 + n*16 + lr;
          C[(size_t)row*N + col] = bf16rn(acc[m][n][r]);
        }
      }
    }
  }
}

// ---------------- output projection: out[t][v] = HTt[t,:]·Woutb[v,:] + bout[v] ----------------
__global__ __launch_bounds__(256) void k_mout(const unsigned short* __restrict__ A,
    const unsigned short* __restrict__ Bt, const float* __restrict__ bias,
    float* __restrict__ out)
{
  __shared__ __align__(16) unsigned short As[64*128];
  __shared__ __align__(16) unsigned short Bs[128*128];
  int tid = threadIdx.x;
  int l   = tid & 63;
  int wid = tid >> 6;
  int col0 = blockIdx.x * 128;
  int lr = l & 15, kg = l >> 4;

  #pragma unroll
  for (int c = 0; c < 4; ++c){                     // A: 16 chunks of 1KB (4 rows each)
    int chunk = wid*4 + c;
    const unsigned short* ga = A + (size_t)(chunk*4 + (l >> 4))*128 + (l & 15)*8;
    __builtin_amdgcn_global_load_lds(
        (const __attribute__((address_space(1))) void*)ga,
        (__attribute__((address_space(3))) void*)(As + chunk*512), 16, 0, 0);
  }
  #pragma unroll
  for (int c = 0; c < 8; ++c){                     // B: 32 chunks of 1KB (4 rows each)
    int chunk = wid*8 + c;
    int brow = col0 + chunk*4 + (l >> 4);
    if (brow > VOCAB-1) brow = VOCAB-1;
    const unsigned short* gb = Bt + (size_t)brow*128 + (l & 15)*8;
    __builtin_amdgcn_global_load_lds(
        (const __attribute__((address_space(1))) void*)gb,
        (__attribute__((address_space(3))) void*)(Bs + chunk*512), 16, 0, 0);
  }
  __syncthreads();

  f32x4 acc[4][2] = {};
  #pragma unroll
  for (int ks = 0; ks < 4; ++ks){
    bf16x8 af[4], bfr[2];
    #pragma unroll
    for (int m = 0; m < 4; ++m)
      af[m] = *(const bf16x8*)(As + (m*16 + lr)*128 + ks*32 + kg*8);
    #pragma unroll
    for (int n = 0; n < 2; ++n)
      bfr[n] = *(const bf16x8*)(Bs + (wid*32 + n*16 + lr)*128 + ks*32 + kg*8);
    #pragma unroll
    for (int m = 0; m < 4; ++m)
      #pragma unroll
      for (int n = 0; n < 2; ++n)
        acc[m][n] = __builtin_amdgcn_mfma_f32_16x16x32_bf16(af[m], bfr[n], acc[m][n], 0, 0, 0);
  }

  #pragma unroll
  for (int n = 0; n < 2; ++n){
    int col = col0 + wid*32 + n*16 + lr;
    if (col < VOCAB){
      float bv = bias[col];
      #pragma unroll
      for (int m = 0; m < 4; ++m){
        #pragma unroll
        for (int r = 0; r < 4; ++r){
          int trow = m*16 + kg*4 + r;              // t in 0..63
          out[(size_t)trow*VOCAB + col] = acc[m][n][r] + bv;
        }
      }
    }
  }
}

// ---------------- GAT layer 1 (heads=4, 128ch), bf16 in/out, wave/node ----------------
__global__ __launch_bounds__(256) void k_gat1(const unsigned short* __restrict__ xlr,
    const int* __restrict__ esrc, const int* __restrict__ offs,
    const float* __restrict__ att, const float* __restrict__ b1,
    unsigned short* __restrict__ h1b)
{
  int node = blockIdx.x*4 + (threadIdx.x >> 6);
  int l = threadIdx.x & 63;
  const unsigned short* bi = xlr + (size_t)node*1024;
  ushort4 u;
  u = *(const ushort4*)(bi + 512 + 4*l);
  float4 xr1; xr1.x = upf(u.x); xr1.y = upf(u.y); xr1.z = upf(u.z); xr1.w = upf(u.w);
  u = *(const ushort4*)(bi + 768 + 4*l);
  float4 xr2; xr2.x = upf(u.x); xr2.y = upf(u.y); xr2.z = upf(u.z); xr2.w = upf(u.w);
  int hq = l >> 5;
  float4 at1 = *(const float4*)(att + hq*HIDC + ((4*l) & 127));
  float4 at2 = *(const float4*)(att + (2+hq)*HIDC + ((4*l) & 127));
  float4 ac1 = {0,0,0,0}, ac2 = {0,0,0,0};
  float d1 = 0.f, d2 = 0.f;
  int beg = offs[node], end = offs[node+1];
  for (int p = beg-1; p < end; ++p){
    int s = (p < beg) ? node : esrc[p];
    const unsigned short* bs = xlr + (size_t)s*1024;
    ushort4 u1 = *(const ushort4*)(bs + 4*l);
    ushort4 u2 = *(const ushort4*)(bs + 256 + 4*l);
    float4 x1; x1.x = upf(u1.x); x1.y = upf(u1.y); x1.z = upf(u1.z); x1.w = upf(u1.w);
    float4 x2; x2.x = upf(u2.x); x2.y = upf(u2.y); x2.z = upf(u2.z); x2.w = upf(u2.w);
    float p1 = leaky(x1.x+xr1.x)*at1.x + leaky(x1.y+xr1.y)*at1.y
             + leaky(x1.z+xr1.z)*at1.z + leaky(x1.w+xr1.w)*at1.w;
    float p2 = leaky(x2.x+xr2.x)*at2.x + leaky(x2.y+xr2.y)*at2.y
             + leaky(x2.z+xr2.z)*at2.z + leaky(x2.w+xr2.w)*at2.w;
    #pragma unroll
    for (int m = 1; m <= 16; m <<= 1){
      p1 += __shfl_xor(p1, m);
      p2 += __shfl_xor(p2, m);
    }
    float w1 = __expf(p1), w2 = __expf(p2);
    ac1.x = fmaf(w1, x1.x, ac1.x); ac1.y = fmaf(w1, x1.y, ac1.y);
    ac1.z = fmaf(w1, x1.z, ac1.z); ac1.w = fmaf(w1, x1.w, ac1.w);
    ac2.x = fmaf(w2, x2.x, ac2.x); ac2.y = fmaf(w2, x2.y, ac2.y);
    ac2.z = fmaf(w2, x2.z, ac2.z); ac2.w = fmaf(w2, x2.w, ac2.w);
    d1 += w1; d2 += w2;
  }
  float i1 = 1.f/d1, i2 = 1.f/d2;
  const float* bq1 = b1 + 4*l;
  const float* bq2 = b1 + 256 + 4*l;
  ushort4 o1, o2;
  o1.x = bf16rn(eluf(ac1.x*i1 + bq1[0])); o1.y = bf16rn(eluf(ac1.y*i1 + bq1[1]));
  o1.z = bf16rn(eluf(ac1.z*i1 + bq1[2])); o1.w = bf16rn(eluf(ac1.w*i1 + bq1[3]));
  o2.x = bf16rn(eluf(ac2.x*i2 + bq2[0])); o2.y = bf16rn(eluf(ac2.y*i2 + bq2[1]));
  o2.z = bf16rn(eluf(ac2.z*i2 + bq2[2])); o2.w = bf16rn(eluf(ac2.w*i2 + bq2[3]));
  *(ushort4*)(h1b + (size_t)node*512 + 4*l)       = o1;
  *(ushort4*)(h1b + (size_t)node*512 + 256 + 4*l) = o2;
}

// ---------------- GAT layer 2 (1 head, 128 ch), bf16 in, f32 out ----------------
__global__ __launch_bounds__(256) void k_gat2(const unsigned short* __restrict__ xlr2,
    const int* __restrict__ esrc, const int* __restrict__ offs,
    const float* __restrict__ att2, const float* __restrict__ b2,
    float* __restrict__ enc)
{
  int node = blockIdx.x*4 + (threadIdx.x >> 6);
  int l = threadIdx.x & 63;
  const unsigned short* bi = xlr2 + (size_t)node*256;
  ushort2 v = *(const ushort2*)(bi + 128 + 2*l);
  float2 xr; xr.x = upf(v.x); xr.y = upf(v.y);
  float2 at = *(const float2*)(att2 + 2*l);
  float2 ac = {0,0}; float den = 0.f;
  int beg = offs[node], end = offs[node+1];
  for (int p = beg-1; p < end; ++p){
    int s = (p < beg) ? node : esrc[p];
    ushort2 xv = *(const ushort2*)(xlr2 + (size_t)s*256 + 2*l);
    float2 x; x.x = upf(xv.x); x.y = upf(xv.y);
    float pp = leaky(x.x+xr.x)*at.x + leaky(x.y+xr.y)*at.y;
    #pragma unroll
    for (int m = 1; m <= 32; m <<= 1) pp += __shfl_xor(pp, m);
    float w = __expf(pp);
    ac.x = fmaf(w, x.x, ac.x); ac.y = fmaf(w, x.y, ac.y);
    den += w;
  }
  float inv = 1.f/den;
  float2 o; o.x = ac.x*inv + b2[2*l]; o.y = ac.y*inv + b2[2*l+1];
  *(float2*)(enc + (size_t)node*128 + 2*l) = o;
}

// ---------------- context mean ----------------
__global__ void k_mean(const float* __restrict__ enc, float* __restrict__ ctx){
  int c = threadIdx.x & 127;
  int slice = blockIdx.x*2 + (threadIdx.x >> 7);
  float s = 0.f;
  for (int i = slice; i < NNODES; i += 160) s += enc[(size_t)i*128 + c];
  atomicAdd(&ctx[c], s * (1.f/NNODES));
}

// ---------------- GRU input precompute: Gi[t] = Wih @ x_t + bih ----------------
__global__ __launch_bounds__(384) void k_gi(const int* __restrict__ tseq,
    const float* __restrict__ emb, const float* __restrict__ ctx,
    const float* __restrict__ Wih, const float* __restrict__ bih,
    float* __restrict__ Gi)
{
  __shared__ float xs[384];
  int t = blockIdx.x, tid = threadIdx.x;
  int tok = (t == 0) ? 0 : tseq[t-1];
  if (tid < 256) xs[tid] = emb[(size_t)tok*EDIM + tid];
  else           xs[tid] = ctx[tid - 256];
  __syncthreads();
  const float* w = Wih + (size_t)tid*384;
  float acc = bih[tid];
  #pragma unroll 8
  for (int k = 0; k < 384; k++) acc = fmaf(w[k], xs[k], acc);
  Gi[t*384 + tid] = acc;
}

// ---------------- GRU recurrence (R5 version, measured 60.2us): one block, 384 threads ----------------
__global__ __launch_bounds__(384) void k_gru(const float* __restrict__ Gi,
    const float* __restrict__ Whh, const float* __restrict__ bhh,
    unsigned short* __restrict__ HTt)
{
  __shared__ float GH[384];
  __shared__ alignas(16) float HS[128];
  int tid = threadIdx.x;
  float w[128];
  {
    const float4* wrow = (const float4*)(Whh + (size_t)tid*HIDC);
    #pragma unroll
    for (int k = 0; k < 32; k++){
      float4 v = wrow[k];
      w[4*k+0] = v.x; w[4*k+1] = v.y; w[4*k+2] = v.z; w[4*k+3] = v.w;
    }
  }
  float bh = bhh[tid];
  float hloc = 0.f;
  if (tid < 128) HS[tid] = 0.f;
  __syncthreads();

  const float4* H4 = (const float4*)HS;

  for (int t = 0; t < TLEN; t++){
    float gi0 = 0.f, gi1 = 0.f, gi2 = 0.f;
    if (tid < 128){
      gi0 = Gi[t*384 + tid];
      gi1 = Gi[t*384 + 128 + tid];
      gi2 = Gi[t*384 + 256 + tid];
    }
    float a0 = 0.f, a1 = 0.f, a2 = 0.f, a3 = 0.f;
    #pragma unroll
    for (int q = 0; q < 16; q++){
      float4 ha = H4[2*q];
      float4 hb = H4[2*q+1];
      a0 = fmaf(w[8*q+0], ha.x, a0);
      a1 = fmaf(w[8*q+1], ha.y, a1);
      a2 = fmaf(w[8*q+2], ha.z, a2);
      a3 = fmaf(w[8*q+3], ha.w, a3);
      a0 = fmaf(w[8*q+4], hb.x, a0);
      a1 = fmaf(w[8*q+5], hb.y, a1);
      a2 = fmaf(w[8*q+6], hb.z, a2);
      a3 = fmaf(w[8*q+7], hb.w, a3);
    }
    float acc = ((a0 + a1) + (a2 + a3)) + bh;
    if (tid >= 128) GH[tid] = acc;
    __syncthreads();
    if (tid < 128){
      float gr = gi0 + acc;
      float gz = gi1 + GH[128 + tid];
      float hn = GH[256 + tid];
      float r = sigm(gr);
      float z = sigm(gz);
      float e2 = __expf(2.f*(gi2 + r*hn));
      float cand = __fdividef(e2 - 1.f, e2 + 1.f);
      float hnew = (1.f - z)*cand + z*hloc;
      hloc = hnew;
      HS[tid] = hnew;
      HTt[t*HIDC + tid] = bf16rn(hnew);
    }
    __syncthreads();
  }
}

// ---------------- launch ----------------
extern "C" void kernel_launch(void* const* d_in, const int* in_sizes, int n_in,
                              void* d_out, int out_size, void* d_ws, size_t ws_size,
                              hipStream_t stream)
{
  const int*   x_nodes = (const int*)  d_in[0];
  const int*   eidx    = (const int*)  d_in[1];   // [2][160000]: src then dst
  const int*   tseq    = (const int*)  d_in[2];
  const float* emb     = (const float*)d_in[3];
  const float* W1l     = (const float*)d_in[4];
  const float* W1r     = (const float*)d_in[5];
  const float* att1    = (const float*)d_in[6];
  const float* b1      = (const float*)d_in[7];
  const float* W2l     = (const float*)d_in[8];
  const float* W2r     = (const float*)d_in[9];
  const float* att2    = (const float*)d_in[10];
  const float* b2      = (const float*)d_in[11];
  const float* Wih     = (const float*)d_in[12];
  const float* Whh     = (const float*)d_in[13];
  const float* bih     = (const float*)d_in[14];
  const float* bhh     = (const float*)d_in[15];
  const float* Wout    = (const float*)d_in[16];
  const float* bout    = (const float*)d_in[17];
  float* out = (float*)d_out;
  char*  ws  = (char*)d_ws;

  // workspace layout (bytes), no aliasing
  unsigned short* xlr1b  = (unsigned short*)(ws);              // 10000*1024*2 = 20,480,000
  unsigned short* h1b    = (unsigned short*)(ws + 20480000);   // 10000*512*2  = 10,240,000
  unsigned short* featsb = (unsigned short*)(ws + 30720000);   // 10000*256*2  =  5,120,000
  unsigned short* xlr2b  = (unsigned short*)(ws + 35840000);   // 10000*256*2  =  5,120,000
  float*          enc    = (float*)        (ws + 40960000);    // 10000*128*4  =  5,120,000
  unsigned short* Bt1    = (unsigned short*)(ws + 46080000);   // 1024*256*2   =    524,288
  unsigned short* Bt2    = (unsigned short*)(ws + 46604288);   // 256*512*2    =    262,144
  int*   deg    = (int*)(ws + 46866432);                       // 40,000
  int*   offs   = (int*)(ws + 46906432);                       // 40,004
  int*   cursor = (int*)(ws + 46946436);                       // 40,000
  int*   esrc   = (int*)(ws + 46986436);                       // 640,000
  float* ctx    = (float*)(ws + 47626440);                     // 512
  float* Gi     = (float*)(ws + 47627008);                     // 98,304 (ends 47,725,312)
  unsigned short* HTt   = (unsigned short*)(ws + 47725312);    // 64*128*2 = 16,384
  unsigned short* Woutb = (unsigned short*)(ws + 47741696);    // 50257*128*2 = 12,865,792 (ends 60,607,488)

  k_prep<<<PB_ZERO, 256, 0, stream>>>(x_nodes, emb, featsb, Wout, Woutb,
                                      W1l, W1r, Bt1, W2l, W2r, Bt2,
                                      deg, cursor, ctx);

  k_deg    <<<625, 256, 0, stream>>>(eidx + NEDGES, deg);
  k_scan   <<<1,  1024, 0, stream>>>(deg, offs);
  k_scatter<<<625, 256, 0, stream>>>(eidx, eidx + NEDGES, offs, cursor, esrc);

  k_mfma<256><<<dim3(79,8), 256, 0, stream>>>(featsb, Bt1, xlr1b, NNODES, 1024);
  k_gat1<<<2500, 256, 0, stream>>>(xlr1b, esrc, offs, att1, b1, h1b);

  k_mfma<512><<<dim3(79,2), 256, 0, stream>>>(h1b, Bt2, xlr2b, NNODES, 256);
  k_gat2<<<2500, 256, 0, stream>>>(xlr2b, esrc, offs, att2, b2, enc);

  k_mean<<<80, 256, 0, stream>>>(enc, ctx);
  k_gi  <<<TLEN, 384, 0, stream>>>(tseq, emb, ctx, Wih, bih, Gi);
  k_gru <<<1, 384, 0, stream>>>(Gi, Whh, bhh, HTt);

  k_mout<<<393, 256, 0, stream>>>(HTt, Woutb, bout, out);
}